// Round 2
// baseline (6593.789 us; speedup 1.0000x reference)
//
#include <hip/hip_runtime.h>
#include <hip/hip_bf16.h>

#define TE  32    // edges per block-tile
#define TV  32    // variables per block-tile
#define DD  128   // D
#define FE  16    // edge feature dim
#define DIN 145   // D + Fe + 1
#define DINP 148  // padded row stride (float4-aligned)
#define HQ  256   // hidden width (Hm = Hag = Ha)

// log_sigmoid(x) = min(x,0) - log(1 + exp(-|x|))  (stable form)
__device__ __forceinline__ float logsig(float x) {
    return fminf(x, 0.f) - __logf(1.f + __expf(-fabsf(x)));
}

// ---------------------------------------------------------------------------
// Edge stage: x = [vs | ef | sign*sol[idx]]  ->  ls(ls(x@W1m^T+b1m)@W2m^T)
// then atomic segment-sum into agg[V][256] (f32).
// Block = 256 threads, tile = 32 edges. Thread j owns hidden column j.
// ---------------------------------------------------------------------------
__global__ __launch_bounds__(256) void edge_kernel(
    const float* __restrict__ vs, const float* __restrict__ ef,
    const float* __restrict__ sol, const float* __restrict__ W1m,
    const float* __restrict__ b1m, const float* __restrict__ W2m,
    const int* __restrict__ vidx, const int* __restrict__ esign,
    float* __restrict__ agg, int E)
{
    __shared__ float xs[TE][DINP];   // 18.9 KB
    __shared__ float h1s[TE][HQ];    // 32 KB
    const int tid = threadIdx.x;
    const int e0 = blockIdx.x * TE;

    // ---- stage 0: gather + concat x tile into LDS ----
    for (int i = tid; i < TE * DIN; i += 256) {
        int e = i / DIN;
        int k = i - e * DIN;
        int ge = e0 + e;
        float v = 0.f;
        if (ge < E) {
            if (k < DD)            v = vs[(size_t)ge * DD + k];
            else if (k < DD + FE)  v = ef[(size_t)ge * FE + (k - DD)];
            else                   v = (float)esign[ge] * sol[vidx[ge]];
        }
        xs[e][k] = v;
    }
    __syncthreads();

    // ---- stage 1: h1[e][tid] = ls(dot(W1m[tid,:], x[e,:]) + b1m[tid]) ----
    {
        float acc[TE];
        #pragma unroll
        for (int e = 0; e < TE; ++e) acc[e] = 0.f;
        const float* wrow = W1m + (size_t)tid * DIN;  // row stride 145 f32 (4B aligned)
        for (int k = 0; k < DIN - 1; k += 4) {
            float w0 = wrow[k];
            float w1 = wrow[k + 1];
            float w2 = wrow[k + 2];
            float w3 = wrow[k + 3];
            #pragma unroll
            for (int e = 0; e < TE; ++e) {
                float4 xv = *(const float4*)&xs[e][k];   // broadcast ds_read_b128
                acc[e] = fmaf(w3, xv.w, fmaf(w2, xv.z, fmaf(w1, xv.y, fmaf(w0, xv.x, acc[e]))));
            }
        }
        {   // K tail (k = 144)
            float w0 = wrow[DIN - 1];
            #pragma unroll
            for (int e = 0; e < TE; ++e) acc[e] = fmaf(w0, xs[e][DIN - 1], acc[e]);
        }
        float b = b1m[tid];
        #pragma unroll
        for (int e = 0; e < TE; ++e) h1s[e][tid] = logsig(acc[e] + b);
    }
    __syncthreads();

    // ---- stage 2: s[e][tid] = ls(dot(W2m[tid,:], h1[e,:])); atomic agg ----
    {
        float acc[TE];
        #pragma unroll
        for (int e = 0; e < TE; ++e) acc[e] = 0.f;
        const float* wrow = W2m + (size_t)tid * HQ;   // row stride 1024 B -> float4 ok
        for (int k = 0; k < HQ; k += 4) {
            float4 wv = *(const float4*)(wrow + k);
            #pragma unroll
            for (int e = 0; e < TE; ++e) {
                float4 hv = *(const float4*)&h1s[e][k];
                acc[e] = fmaf(wv.w, hv.w, fmaf(wv.z, hv.z, fmaf(wv.y, hv.y, fmaf(wv.x, hv.x, acc[e]))));
            }
        }
        for (int e = 0; e < TE; ++e) {
            int ge = e0 + e;
            if (ge < E) {
                float sv = logsig(acc[e]);
                // thread j -> column j: contiguous across the wave -> coalesced atomics
                atomicAdd(&agg[(size_t)vidx[ge] * HQ + tid], sv);
            }
        }
    }
}

// ---------------------------------------------------------------------------
// Variable stage: h = ls(ls(agg@W1a^T+b1a)@W2a^T);  out = h@Wc^T + bc
// Block = 256 threads, tile = 32 variables.
// ---------------------------------------------------------------------------
__global__ __launch_bounds__(256) void var_kernel(
    const float* __restrict__ agg,
    const float* __restrict__ W1a, const float* __restrict__ b1a,
    const float* __restrict__ W2a, const float* __restrict__ Wc,
    const float* __restrict__ bc, float* __restrict__ out, int V)
{
    __shared__ float as[TV][HQ];    // 32 KB
    __shared__ float h1s[TV][HQ];   // 32 KB
    __shared__ float hs[TV][DD];    // 16 KB
    const int tid = threadIdx.x;
    const int v0 = blockIdx.x * TV;

    // ---- load agg tile (coalesced float4) ----
    for (int i = tid; i < TV * (HQ / 4); i += 256) {
        int v = i >> 6;             // 64 float4 per row
        int k = (i & 63) << 2;
        int gv = v0 + v;
        float4 val = make_float4(0.f, 0.f, 0.f, 0.f);
        if (gv < V) val = *(const float4*)&agg[(size_t)gv * HQ + k];
        *(float4*)&as[v][k] = val;
    }
    __syncthreads();

    // ---- stage 1: h1[v][tid] = ls(dot(W1a[tid,:], agg[v,:]) + b1a[tid]) ----
    {
        float acc[TV];
        #pragma unroll
        for (int v = 0; v < TV; ++v) acc[v] = 0.f;
        const float* wrow = W1a + (size_t)tid * HQ;
        for (int k = 0; k < HQ; k += 4) {
            float4 wv = *(const float4*)(wrow + k);
            #pragma unroll
            for (int v = 0; v < TV; ++v) {
                float4 av = *(const float4*)&as[v][k];
                acc[v] = fmaf(wv.w, av.w, fmaf(wv.z, av.z, fmaf(wv.y, av.y, fmaf(wv.x, av.x, acc[v]))));
            }
        }
        float b = b1a[tid];
        #pragma unroll
        for (int v = 0; v < TV; ++v) h1s[v][tid] = logsig(acc[v] + b);
    }
    __syncthreads();

    // ---- stage 2: h[v][col] = ls(dot(W2a[col,:], h1[v,:])), col in [0,128) ----
    {
        const int col = tid & (DD - 1);
        const int vb = (tid >> 7) << 4;     // threads 0-127: vars 0-15; 128-255: vars 16-31
        float acc[16];
        #pragma unroll
        for (int i = 0; i < 16; ++i) acc[i] = 0.f;
        const float* wrow = W2a + (size_t)col * HQ;
        for (int k = 0; k < HQ; k += 4) {
            float4 wv = *(const float4*)(wrow + k);
            #pragma unroll
            for (int i = 0; i < 16; ++i) {
                float4 hv = *(const float4*)&h1s[vb + i][k];
                acc[i] = fmaf(wv.w, hv.w, fmaf(wv.z, hv.z, fmaf(wv.y, hv.y, fmaf(wv.x, hv.x, acc[i]))));
            }
        }
        #pragma unroll
        for (int i = 0; i < 16; ++i) hs[vb + i][col] = logsig(acc[i]);
    }
    __syncthreads();

    // ---- stage 3: out[v][p] = dot(Wc[p,:], h[v,:]) + bc[p] ----
    if (tid < TV * 2) {
        int v = tid >> 1, p = tid & 1;
        int gv = v0 + v;
        if (gv < V) {
            const float* wrow = Wc + (size_t)p * DD;
            float acc = bc[p];
            for (int k = 0; k < DD; k += 4) {
                float4 wv = *(const float4*)(wrow + k);
                float4 hv = *(const float4*)&hs[v][k];
                acc = fmaf(wv.w, hv.w, fmaf(wv.z, hv.z, fmaf(wv.y, hv.y, fmaf(wv.x, hv.x, acc))));
            }
            out[(size_t)gv * 2 + p] = acc;
        }
    }
}

extern "C" void kernel_launch(void* const* d_in, const int* in_sizes, int n_in,
                              void* d_out, int out_size, void* d_ws, size_t ws_size,
                              hipStream_t stream) {
    const float* vs  = (const float*)d_in[0];   // variable_state [E,128] f32
    const float* ef  = (const float*)d_in[1];   // edge_feature   [E,16]  f32
    const float* sol = (const float*)d_in[2];   // solution       [V]     f32
    const float* W1m = (const float*)d_in[3];   // [256,145]
    const float* b1m = (const float*)d_in[4];   // [256]
    const float* W2m = (const float*)d_in[5];   // [256,256]
    const float* W1a = (const float*)d_in[6];   // [256,256]
    const float* b1a = (const float*)d_in[7];   // [256]
    const float* W2a = (const float*)d_in[8];   // [128,256]
    const float* Wc  = (const float*)d_in[9];   // [2,128]
    const float* bc  = (const float*)d_in[10];  // [2]
    const int* vidx  = (const int*)d_in[11];    // [E]
    const int* sgn   = (const int*)d_in[12];    // [E]

    const int E = in_sizes[0] / DD;
    const int V = in_sizes[2];

    float* agg = (float*)d_ws;                  // [V,256] f32 = 204.8 MB scratch
    hipMemsetAsync(agg, 0, (size_t)V * HQ * sizeof(float), stream);

    edge_kernel<<<dim3((E + TE - 1) / TE), dim3(256), 0, stream>>>(
        vs, ef, sol, W1m, b1m, W2m, vidx, sgn, agg, E);
    var_kernel<<<dim3((V + TV - 1) / TV), dim3(256), 0, stream>>>(
        agg, W1a, b1a, W2a, Wc, bc, (float*)d_out, V);
}

// Round 3
// 1768.677 us; speedup vs baseline: 3.7281x; 3.7281x over previous
//
#include <hip/hip_runtime.h>
#include <hip/hip_bf16.h>

typedef unsigned short u16;
typedef __attribute__((ext_vector_type(8))) short   short8;
typedef __attribute__((ext_vector_type(8))) __bf16  bf16x8;
typedef __attribute__((ext_vector_type(16))) float  floatx16;

#define DD  128   // D
#define FE  16    // edge feature dim
#define DIN 145   // D + Fe + 1
#define K1  160   // Din padded to multiple of 16
#define K1P 168   // xs LDS row stride (shorts): 336 B = 21 x 16B granules (odd -> spread banks)
#define HQ  256   // hidden width
#define HQP 264   // h1 LDS row stride (shorts): 528 B = 33 x 16B granules
#define ME  64    // edges per block   (E = 1,000,000 is divisible by 64)
#define MV  32    // variables per block (V = 200,000 is divisible by 32)

__device__ __forceinline__ float logsig(float x) {
    return fminf(x, 0.f) - __logf(1.f + __expf(-fabsf(x)));
}
// f32 -> bf16 RNE (bit trick; inputs are finite)
__device__ __forceinline__ u16 f2b(float f) {
    union { float f; unsigned u; } x; x.f = f;
    unsigned r = x.u + 0x7fffu + ((x.u >> 16) & 1u);
    return (u16)(r >> 16);
}
__device__ __forceinline__ ushort4 f2b4(float4 v) {
    ushort4 o; o.x = f2b(v.x); o.y = f2b(v.y); o.z = f2b(v.z); o.w = f2b(v.w);
    return o;
}
__device__ __forceinline__ bf16x8 ld_bf8_lds(const short* p) {
    return __builtin_bit_cast(bf16x8, *(const short8*)p);
}
__device__ __forceinline__ bf16x8 ld_bf8_glb(const short* p) {
    return __builtin_bit_cast(bf16x8, *(const short8*)p);
}

// ---------------------------------------------------------------------------
// Weight pre-conversion: f32 -> bf16 copies in workspace (re-done every call;
// d_ws is re-poisoned before each launch). W1m rows padded 145 -> 160 (zeros).
// ---------------------------------------------------------------------------
__global__ __launch_bounds__(256) void conv_weights(
    const float* __restrict__ W1m, const float* __restrict__ W2m,
    const float* __restrict__ W1a, const float* __restrict__ W2a,
    short* __restrict__ W1mb, short* __restrict__ W2mb,
    short* __restrict__ W1ab, short* __restrict__ W2ab)
{
    int i = blockIdx.x * 256 + threadIdx.x;
    if (i < 256 * K1) {                              // W1mb [256][160]
        int n = i / K1, k = i - n * K1;
        W1mb[i] = (k < DIN) ? (short)f2b(W1m[n * DIN + k]) : (short)0;
    } else if (i < 256 * K1 + 256 * HQ) {            // W2mb [256][256]
        int j = i - 256 * K1;
        W2mb[j] = (short)f2b(W2m[j]);
    } else if (i < 256 * K1 + 2 * 256 * HQ) {        // W1ab [256][256]
        int j = i - 256 * K1 - 256 * HQ;
        W1ab[j] = (short)f2b(W1a[j]);
    } else if (i < 256 * K1 + 2 * 256 * HQ + 128 * HQ) { // W2ab [128][256]
        int j = i - 256 * K1 - 2 * 256 * HQ;
        W2ab[j] = (short)f2b(W2a[j]);
    }
}

// ---------------------------------------------------------------------------
// Edge stage (MFMA): x = [vs|ef|sign*sol] -> ls(ls(x@W1m^T+b1m)@W2m^T)
// -> atomic segment-sum into agg[V][256] f32.
// Block = 256 thr = 4 waves; tile = 64 edges; wave w owns hidden cols w*64..+63.
// mfma_f32_32x32x16_bf16: A[m=lane&31][k=(lane>>5)*8+j]; B holds B[k][n] with
// n=lane&31, k=(lane>>5)*8+j (i.e. W[n][k..k+7] contiguous); D: col=lane&31,
// row=(reg&3)+8*(reg>>2)+4*(lane>>5)  [measured m74/m101].
// ---------------------------------------------------------------------------
__global__ __launch_bounds__(256) void edge_mfma(
    const float* __restrict__ vs, const float* __restrict__ ef,
    const float* __restrict__ sol, const float* __restrict__ b1m,
    const short* __restrict__ W1mb, const short* __restrict__ W2mb,
    const int* __restrict__ vidx, const int* __restrict__ esign,
    float* __restrict__ agg, int E)
{
    __shared__ short xs[ME][K1P];    // 21504 B
    __shared__ short h1s[ME][HQP];   // 33792 B
    __shared__ int   vix[ME];        //   256 B  -> total 55552 B => 2 blocks/CU
    const int tid = threadIdx.x;
    const int e0 = blockIdx.x * ME;

    // ---- gather: vs rows (64 x 128 f32 = 2048 float4) ----
    for (int i = tid; i < ME * 32; i += 256) {
        int e = i >> 5, q = (i & 31) << 2;
        float4 v = *(const float4*)&vs[(size_t)(e0 + e) * DD + q];
        *(ushort4*)&xs[e][q] = f2b4(v);
    }
    // ---- ef (64 x 16 f32 = 256 float4) ----
    for (int i = tid; i < ME * 4; i += 256) {
        int e = i >> 2, q = (i & 3) << 2;
        float4 v = *(const float4*)&ef[(size_t)(e0 + e) * FE + q];
        *(ushort4*)&xs[e][DD + q] = f2b4(v);
    }
    // ---- signed solution column + K-pad + vidx ----
    for (int i = tid; i < ME * 16; i += 256) {
        int e = i >> 4, k = i & 15;
        if (k == 0) {
            int gi = vidx[e0 + e];
            vix[e] = gi;
            xs[e][144] = (short)f2b((float)esign[e0 + e] * sol[gi]);
        } else {
            xs[e][144 + k] = 0;
        }
    }
    __syncthreads();

    const int wv = tid >> 6, lane = tid & 63;
    const int lr = lane & 31, lh = lane >> 5;
    const int n0 = wv * 64;

    // ---- layer 1: [64 x 160] @ [160 x 64-chunk] ----
    floatx16 a00 = {}, a01 = {}, a10 = {}, a11 = {};
    #pragma unroll
    for (int ks = 0; ks < K1 / 16; ++ks) {
        int k = ks * 16 + lh * 8;
        bf16x8 A0 = ld_bf8_lds(&xs[lr][k]);
        bf16x8 A1 = ld_bf8_lds(&xs[32 + lr][k]);
        bf16x8 B0 = ld_bf8_glb(&W1mb[(size_t)(n0 + lr) * K1 + k]);
        bf16x8 B1 = ld_bf8_glb(&W1mb[(size_t)(n0 + 32 + lr) * K1 + k]);
        a00 = __builtin_amdgcn_mfma_f32_32x32x16_bf16(A0, B0, a00, 0, 0, 0);
        a01 = __builtin_amdgcn_mfma_f32_32x32x16_bf16(A0, B1, a01, 0, 0, 0);
        a10 = __builtin_amdgcn_mfma_f32_32x32x16_bf16(A1, B0, a10, 0, 0, 0);
        a11 = __builtin_amdgcn_mfma_f32_32x32x16_bf16(A1, B1, a11, 0, 0, 0);
    }
    {
        float bn0 = b1m[n0 + lr], bn1 = b1m[n0 + 32 + lr];
        #pragma unroll
        for (int r = 0; r < 16; ++r) {
            int row = (r & 3) + 8 * (r >> 2) + 4 * lh;
            h1s[row][n0 + lr]           = (short)f2b(logsig(a00[r] + bn0));
            h1s[row][n0 + 32 + lr]      = (short)f2b(logsig(a01[r] + bn1));
            h1s[32 + row][n0 + lr]      = (short)f2b(logsig(a10[r] + bn0));
            h1s[32 + row][n0 + 32 + lr] = (short)f2b(logsig(a11[r] + bn1));
        }
    }
    __syncthreads();

    // ---- layer 2: [64 x 256] @ [256 x 64-chunk] ----
    a00 = (floatx16){}; a01 = (floatx16){}; a10 = (floatx16){}; a11 = (floatx16){};
    #pragma unroll
    for (int ks = 0; ks < HQ / 16; ++ks) {
        int k = ks * 16 + lh * 8;
        bf16x8 A0 = ld_bf8_lds(&h1s[lr][k]);
        bf16x8 A1 = ld_bf8_lds(&h1s[32 + lr][k]);
        bf16x8 B0 = ld_bf8_glb(&W2mb[(size_t)(n0 + lr) * HQ + k]);
        bf16x8 B1 = ld_bf8_glb(&W2mb[(size_t)(n0 + 32 + lr) * HQ + k]);
        a00 = __builtin_amdgcn_mfma_f32_32x32x16_bf16(A0, B0, a00, 0, 0, 0);
        a01 = __builtin_amdgcn_mfma_f32_32x32x16_bf16(A0, B1, a01, 0, 0, 0);
        a10 = __builtin_amdgcn_mfma_f32_32x32x16_bf16(A1, B0, a10, 0, 0, 0);
        a11 = __builtin_amdgcn_mfma_f32_32x32x16_bf16(A1, B1, a11, 0, 0, 0);
    }
    // ---- epilogue: logsig + coalesced f32 atomics into agg ----
    #pragma unroll
    for (int r = 0; r < 16; ++r) {
        int row = (r & 3) + 8 * (r >> 2) + 4 * lh;
        int va = vix[row], vb = vix[32 + row];
        atomicAdd(&agg[(size_t)va * HQ + n0 + lr],      logsig(a00[r]));
        atomicAdd(&agg[(size_t)va * HQ + n0 + 32 + lr], logsig(a01[r]));
        atomicAdd(&agg[(size_t)vb * HQ + n0 + lr],      logsig(a10[r]));
        atomicAdd(&agg[(size_t)vb * HQ + n0 + 32 + lr], logsig(a11[r]));
    }
}

// ---------------------------------------------------------------------------
// Variable stage (MFMA): h = ls(ls(agg@W1a^T+b1a)@W2a^T); out = h@Wc^T + bc
// Block = 256 thr = 4 waves; tile = 32 variables. 50.7 KB LDS -> 3 blocks/CU.
// ---------------------------------------------------------------------------
__global__ __launch_bounds__(256) void var_mfma(
    const float* __restrict__ agg, const float* __restrict__ b1a,
    const short* __restrict__ W1ab, const short* __restrict__ W2ab,
    const float* __restrict__ Wc, const float* __restrict__ bc,
    float* __restrict__ out, int V)
{
    __shared__ short as_s[MV][HQP];     // 16896 B
    __shared__ short h1v[MV][HQP];      // 16896 B
    __shared__ float hsv[MV][DD + 4];   // 16896 B
    const int tid = threadIdx.x;
    const int v0 = blockIdx.x * MV;

    // ---- load agg tile (32 x 256 f32 = 2048 float4), convert to bf16 ----
    for (int i = tid; i < MV * 64; i += 256) {
        int v = i >> 6, q = (i & 63) << 2;
        float4 a = *(const float4*)&agg[(size_t)(v0 + v) * HQ + q];
        *(ushort4*)&as_s[v][q] = f2b4(a);
    }
    __syncthreads();

    const int wv = tid >> 6, lane = tid & 63;
    const int lr = lane & 31, lh = lane >> 5;
    const int n0 = wv * 64;

    // ---- layer 1: M=32, N=64/wave, K=256 ----
    floatx16 c0 = {}, c1 = {};
    #pragma unroll
    for (int ks = 0; ks < HQ / 16; ++ks) {
        int k = ks * 16 + lh * 8;
        bf16x8 A  = ld_bf8_lds(&as_s[lr][k]);
        bf16x8 B0 = ld_bf8_glb(&W1ab[(size_t)(n0 + lr) * HQ + k]);
        bf16x8 B1 = ld_bf8_glb(&W1ab[(size_t)(n0 + 32 + lr) * HQ + k]);
        c0 = __builtin_amdgcn_mfma_f32_32x32x16_bf16(A, B0, c0, 0, 0, 0);
        c1 = __builtin_amdgcn_mfma_f32_32x32x16_bf16(A, B1, c1, 0, 0, 0);
    }
    {
        float bn0 = b1a[n0 + lr], bn1 = b1a[n0 + 32 + lr];
        #pragma unroll
        for (int r = 0; r < 16; ++r) {
            int row = (r & 3) + 8 * (r >> 2) + 4 * lh;  // rows 0..31 (M=32 => lh adds within tile)
            h1v[row][n0 + lr]      = (short)f2b(logsig(c0[r] + bn0));
            h1v[row][n0 + 32 + lr] = (short)f2b(logsig(c1[r] + bn1));
        }
    }
    __syncthreads();

    // ---- layer 2: M=32, N=32/wave (cols wv*32..+31), K=256 ----
    floatx16 d0 = {};
    const int n0b = wv * 32;
    #pragma unroll
    for (int ks = 0; ks < HQ / 16; ++ks) {
        int k = ks * 16 + lh * 8;
        bf16x8 A = ld_bf8_lds(&h1v[lr][k]);
        bf16x8 B = ld_bf8_glb(&W2ab[(size_t)(n0b + lr) * HQ + k]);
        d0 = __builtin_amdgcn_mfma_f32_32x32x16_bf16(A, B, d0, 0, 0, 0);
    }
    #pragma unroll
    for (int r = 0; r < 16; ++r) {
        int row = (r & 3) + 8 * (r >> 2) + 4 * lh;
        hsv[row][n0b + lr] = logsig(d0[r]);
    }
    __syncthreads();

    // ---- classifier: out[v][p] = dot(Wc[p,:], h[v,:]) + bc[p] (f32) ----
    if (tid < MV * 2) {
        int v = tid >> 1, p = tid & 1;
        const float* wrow = Wc + (size_t)p * DD;
        float acc = bc[p];
        for (int k = 0; k < DD; k += 4) {
            float4 w4 = *(const float4*)&wrow[k];
            float4 h4 = *(const float4*)&hsv[v][k];
            acc = fmaf(w4.w, h4.w, fmaf(w4.z, h4.z, fmaf(w4.y, h4.y, fmaf(w4.x, h4.x, acc))));
        }
        out[(size_t)(v0 + v) * 2 + p] = acc;
    }
}

extern "C" void kernel_launch(void* const* d_in, const int* in_sizes, int n_in,
                              void* d_out, int out_size, void* d_ws, size_t ws_size,
                              hipStream_t stream) {
    const float* vs  = (const float*)d_in[0];   // [E,128] f32
    const float* ef  = (const float*)d_in[1];   // [E,16]
    const float* sol = (const float*)d_in[2];   // [V]
    const float* W1m = (const float*)d_in[3];   // [256,145]
    const float* b1m = (const float*)d_in[4];   // [256]
    const float* W2m = (const float*)d_in[5];   // [256,256]
    const float* W1a = (const float*)d_in[6];   // [256,256]
    const float* b1a = (const float*)d_in[7];   // [256]
    const float* W2a = (const float*)d_in[8];   // [128,256]
    const float* Wc  = (const float*)d_in[9];   // [2,128]
    const float* bc  = (const float*)d_in[10];  // [2]
    const int* vidx  = (const int*)d_in[11];    // [E]
    const int* sgn   = (const int*)d_in[12];    // [E]

    const int E = in_sizes[0] / DD;   // 1,000,000 (divisible by 64)
    const int V = in_sizes[2];        //   200,000 (divisible by 32)

    char* ws = (char*)d_ws;
    float* agg = (float*)ws;                          // [V,256] f32 = 204.8 MB
    size_t off = (size_t)V * HQ * sizeof(float);
    short* W1mb = (short*)(ws + off); off += (size_t)256 * K1 * 2;  // 80 KB
    short* W2mb = (short*)(ws + off); off += (size_t)256 * HQ * 2;  // 128 KB
    short* W1ab = (short*)(ws + off); off += (size_t)256 * HQ * 2;  // 128 KB
    short* W2ab = (short*)(ws + off);                                // 64 KB

    hipMemsetAsync(agg, 0, (size_t)V * HQ * sizeof(float), stream);
    conv_weights<<<dim3(800), dim3(256), 0, stream>>>(
        W1m, W2m, W1a, W2a, W1mb, W2mb, W1ab, W2ab);
    edge_mfma<<<dim3(E / ME), dim3(256), 0, stream>>>(
        vs, ef, sol, b1m, W1mb, W2mb, vidx, sgn, agg, E);
    var_mfma<<<dim3(V / MV), dim3(256), 0, stream>>>(
        agg, b1a, W1ab, W2ab, Wc, bc, (float*)d_out, V);
}